// Round 5
// baseline (623.714 us; speedup 1.0000x reference)
//
#include <hip/hip_runtime.h>
#include <hip/hip_fp16.h>

#define N_NODES 100000
#define N_EDGES 1600000
#define IN_DIM  165
#define HIDDEN  128
#define OUT_DIM 2

#define NBKT 391        // ceil(100000/256) buckets of 256 nodes
#define BCAP 40         // LDS slots per bucket
#define KPAD 176        // 5*32 + 16

typedef _Float16 half8_t __attribute__((ext_vector_type(8)));
typedef _Float16 half4_t __attribute__((ext_vector_type(4)));
typedef float floatx4 __attribute__((ext_vector_type(4)));

// ---------------- degree histogram ----------------

__global__ void k_hist(const int* __restrict__ dst, int* __restrict__ deg) {
    int e = blockIdx.x * blockDim.x + threadIdx.x;
    if (e < N_EDGES) atomicAdd(&deg[dst[e]], 1);
}

// ---------------- scan: deg -> rowptr + dinv ----------------

__global__ __launch_bounds__(1024) void k_scan(const int* __restrict__ deg,
                                               int* __restrict__ rowptr,
                                               float* __restrict__ dinv) {
    __shared__ int wsum[16];
    __shared__ int chunk_total;
    const int NI4 = N_NODES / 4;              // 25000
    const int NCH = (NI4 + 1023) / 1024;      // 25
    int t = threadIdx.x;
    int lane = t & 63, wid = t >> 6;
    const int4* deg4 = (const int4*)deg;
    int running = 0;
    int idx4 = t;
    int4 cur = (idx4 < NI4) ? deg4[idx4] : make_int4(0, 0, 0, 0);
    for (int c = 0; c < NCH; c++) {
        int nidx4 = idx4 + 1024;
        int4 nxt = make_int4(0, 0, 0, 0);
        if (c + 1 < NCH && nidx4 < NI4) nxt = deg4[nidx4];
        int s = cur.x + cur.y + cur.z + cur.w;
        int inc = s;
        #pragma unroll
        for (int off = 1; off < 64; off <<= 1) {
            int y = __shfl_up(inc, off);
            if (lane >= off) inc += y;
        }
        if (lane == 63) wsum[wid] = inc;
        __syncthreads();
        if (t == 0) {
            int acc = 0;
            for (int w = 0; w < 16; w++) { int v = wsum[w]; wsum[w] = acc; acc += v; }
            chunk_total = acc;
        }
        __syncthreads();
        int e = running + wsum[wid] + (inc - s);
        if (idx4 < NI4) {
            int4 r;
            r.x = e;
            r.y = e + cur.x;
            r.z = r.y + cur.y;
            r.w = r.z + cur.z;
            ((int4*)rowptr)[idx4] = r;
            float4 dv;
            dv.x = rsqrtf((float)(cur.x + 1));
            dv.y = rsqrtf((float)(cur.y + 1));
            dv.z = rsqrtf((float)(cur.z + 1));
            dv.w = rsqrtf((float)(cur.w + 1));
            ((float4*)dinv)[idx4] = dv;
        }
        running += chunk_total;
        __syncthreads();
        cur = nxt;
        idx4 = nidx4;
    }
    if (t == 0) rowptr[N_NODES] = running;
}

// ---------------- bucket cursor init ----------------

__global__ void k_binit(const int* __restrict__ rowptr, int* __restrict__ bcursor) {
    int b = blockIdx.x * blockDim.x + threadIdx.x;
    if (b < NBKT) bcursor[b] = rowptr[b << 8];
}

// ---------------- binned fill: edges -> bucket-grouped packed entries ----------------
// entry = src | (dst&255)<<17

__global__ __launch_bounds__(256) void k_fill_bin(const int* __restrict__ src,
                                                  const int* __restrict__ dst,
                                                  int* __restrict__ bcursor,
                                                  unsigned* __restrict__ csr_tmp) {
    __shared__ int bins[NBKT][BCAP];   // 62.6 KB
    __shared__ int bcnt[NBKT];
    int t = threadIdx.x;
    for (int i = t; i < NBKT; i += 256) bcnt[i] = 0;
    __syncthreads();

    const int CHUNK = 4096;
    const int nchunks = (N_EDGES + CHUNK - 1) / CHUNK;   // 391
    int wid = t >> 6, lane = t & 63;

    for (int c = blockIdx.x; c < nchunks; c += gridDim.x) {
        int e0 = c * CHUNK;
        #pragma unroll 4
        for (int j = 0; j < CHUNK / 256; j++) {
            int e = e0 + j * 256 + t;
            if (e < N_EDGES) {
                int s = src[e], d = dst[e];
                int b = d >> 8;
                unsigned entry = (unsigned)s | ((unsigned)(d & 255) << 17);
                int pos = atomicAdd(&bcnt[b], 1);
                if (pos < BCAP) bins[b][pos] = (int)entry;
                else { int g = atomicAdd(&bcursor[b], 1); csr_tmp[g] = entry; }
            }
        }
        __syncthreads();
        // flush full 16-entry runs
        for (int b = wid; b < NBKT; b += 4) {
            int cnt = bcnt[b]; if (cnt > BCAP) cnt = BCAP;
            while (cnt >= 16) {
                int base = 0;
                if (lane == 0) base = atomicAdd(&bcursor[b], 16);
                base = __shfl(base, 0);
                int v = 0, m = 0;
                if (lane < 16) v = bins[b][lane];
                if (lane < cnt - 16) m = bins[b][16 + lane];
                if (lane < 16) csr_tmp[base + lane] = (unsigned)v;
                if (lane < cnt - 16) bins[b][lane] = m;
                cnt -= 16;
            }
            if (lane == 0) bcnt[b] = cnt;
        }
        __syncthreads();
    }
    // final residual flush
    for (int b = wid; b < NBKT; b += 4) {
        int cnt = bcnt[b]; if (cnt > BCAP) cnt = BCAP;
        if (cnt > 0) {
            int base = 0;
            if (lane == 0) base = atomicAdd(&bcursor[b], cnt);
            base = __shfl(base, 0);
            if (lane < cnt) csr_tmp[base + lane] = (unsigned)bins[b][lane];
        }
    }
}

// ---------------- in-bucket counting sort -> final CSR (src only) ----------------

__global__ __launch_bounds__(256) void k_sort(const int* __restrict__ rowptr,
                                              const unsigned* __restrict__ csr_tmp,
                                              int* __restrict__ csr) {
    __shared__ int cur[256];
    int b = blockIdx.x;
    int n0 = b << 8;
    int t = threadIdx.x;
    int node = n0 + t;
    cur[t] = (node < N_NODES) ? rowptr[node] : 0;
    int rbase = rowptr[n0];
    int rend  = rowptr[min(n0 + 256, N_NODES)];
    __syncthreads();
    for (int p = rbase + t; p < rend; p += 256) {
        unsigned entry = csr_tmp[p];
        int local = (int)(entry >> 17);
        int s = (int)(entry & 0x1FFFFu);
        int pos = atomicAdd(&cur[local], 1);
        csr[pos] = s;   // scatter confined to this bucket's ~16KB region
    }
}

// ---------------- W1 transpose to fp16 [col][KPAD] ----------------

__global__ void k_w1t(const float* __restrict__ W1, _Float16* __restrict__ w1t) {
    int idx = blockIdx.x * 256 + threadIdx.x;
    if (idx < HIDDEN * KPAD) {
        int c = idx / KPAD, k = idx - c * KPAD;
        float v = (k < IN_DIM) ? W1[k * HIDDEN + c] : 0.f;
        w1t[idx] = (_Float16)v;
    }
}

// ---------------- GEMM1 (f16 MFMA): h1s = dinv * (x @ W1), fp16 out ----------------
// One wave per 16-row strip; A from global x (fp32->fp16), B from L2-resident W1T.

__global__ __launch_bounds__(256) void k_gemm1(const float* __restrict__ x,
                                               const _Float16* __restrict__ w1t,
                                               const float* __restrict__ dinv,
                                               _Float16* __restrict__ h1s) {
    int t = threadIdx.x;
    int wid = t >> 6, lane = t & 63;
    int row0 = (blockIdx.x * 4 + wid) * 16;
    if (row0 >= N_NODES) return;
    int m = lane & 15;
    int quad = lane >> 4;
    const float* xrow = x + (size_t)(row0 + m) * IN_DIM;

    floatx4 acc[8];
    #pragma unroll
    for (int i = 0; i < 8; i++) acc[i] = (floatx4)(0.f);

    #pragma unroll 1
    for (int kc = 0; kc < 5; kc++) {
        int kb = kc * 32 + quad * 8;
        half8_t a;
        #pragma unroll
        for (int j = 0; j < 8; j++) a[j] = (_Float16)xrow[kb + j];
        #pragma unroll
        for (int cb = 0; cb < 8; cb++) {
            int col = cb * 16 + m;
            half8_t bf = *(const half8_t*)&w1t[col * KPAD + kb];
            acc[cb] = __builtin_amdgcn_mfma_f32_16x16x32_f16(a, bf, acc[cb], 0, 0, 0);
        }
    }
    // K tail: 160..164 via 16x16x16 (k = quad*4 + j)
    {
        int kb = 160 + quad * 4;
        half4_t a;
        #pragma unroll
        for (int j = 0; j < 4; j++)
            a[j] = (kb + j < IN_DIM) ? (_Float16)xrow[kb + j] : (_Float16)0.f;
        #pragma unroll
        for (int cb = 0; cb < 8; cb++) {
            int col = cb * 16 + m;
            half4_t bf = *(const half4_t*)&w1t[col * KPAD + kb];
            acc[cb] = __builtin_amdgcn_mfma_f32_16x16x16f16(a, bf, acc[cb], 0, 0, 0);
        }
    }
    // epilogue: scale by dinv[row], store fp16 (C/D: col=lane&15, row=quad*4+reg)
    float dv[4];
    #pragma unroll
    for (int r = 0; r < 4; r++) dv[r] = dinv[row0 + quad * 4 + r];
    #pragma unroll
    for (int cb = 0; cb < 8; cb++) {
        #pragma unroll
        for (int r = 0; r < 4; r++) {
            h1s[(size_t)(row0 + quad * 4 + r) * HIDDEN + cb * 16 + m] =
                (_Float16)(acc[cb][r] * dv[r]);
        }
    }
}

// ---------------- Fused agg1 + bias + ReLU + W2 (128->2), weightless sum ----------------
// One wave per node; lane f owns features 2f,2f+1. h2s = dinv * (relu(z) @ W2).

__global__ __launch_bounds__(256) void k_agg1(const __half2* __restrict__ h1,
                                              const int* __restrict__ rowptr,
                                              const int* __restrict__ csr,
                                              const float* __restrict__ dinv,
                                              const float* __restrict__ b1,
                                              const float* __restrict__ W2,
                                              float2* __restrict__ h2s) {
    int node = blockIdx.x * 4 + (threadIdx.x >> 6);
    int f = threadIdx.x & 63;
    float2 self = __half22float2(h1[node * 64 + f]);
    float accx = self.x, accy = self.y;
    int p0 = rowptr[node], p1 = rowptr[node + 1];

    int p = p0;
    for (; p + 7 < p1; p += 8) {
        int s[8];
        #pragma unroll
        for (int j = 0; j < 8; j++) s[j] = csr[p + j];
        __half2 g[8];
        #pragma unroll
        for (int j = 0; j < 8; j++) g[j] = h1[s[j] * 64 + f];
        #pragma unroll
        for (int j = 0; j < 8; j++) {
            float2 gf = __half22float2(g[j]);
            accx += gf.x;
            accy += gf.y;
        }
    }
    for (; p < p1; p++) {
        float2 gf = __half22float2(h1[csr[p] * 64 + f]);
        accx += gf.x;
        accy += gf.y;
    }

    float di = dinv[node];
    float2 bb = ((const float2*)b1)[f];
    float z0 = fmaf(di, accx, bb.x);
    float z1 = fmaf(di, accy, bb.y);
    float r0 = fmaxf(z0, 0.f);
    float r1 = fmaxf(z1, 0.f);
    float4 w2v = ((const float4*)W2)[f];
    float a0 = r0 * w2v.x + r1 * w2v.z;
    float a1 = r0 * w2v.y + r1 * w2v.w;
    #pragma unroll
    for (int off = 32; off; off >>= 1) {
        a0 += __shfl_down(a0, off);
        a1 += __shfl_down(a1, off);
    }
    if (f == 0) h2s[node] = make_float2(di * a0, di * a1);
}

// ---------------- agg2: out = b2 + dinv_i*(h2s_i + sum h2s_src) ----------------

__global__ void k_agg2(const float2* __restrict__ h2s, const int* __restrict__ rowptr,
                       const int* __restrict__ csr, const float* __restrict__ dinv,
                       const float* __restrict__ b2, float2* __restrict__ out) {
    int i = blockIdx.x * blockDim.x + threadIdx.x;
    if (i >= N_NODES) return;
    float2 self = h2s[i];
    float a0 = self.x, a1 = self.y;
    int p0 = rowptr[i], p1 = rowptr[i + 1];
    int p = p0;
    for (; p + 3 < p1; p += 4) {
        int s0 = csr[p], s1 = csr[p + 1], s2 = csr[p + 2], s3 = csr[p + 3];
        float2 g0 = h2s[s0], g1 = h2s[s1], g2 = h2s[s2], g3 = h2s[s3];
        a0 += g0.x + g1.x + g2.x + g3.x;
        a1 += g0.y + g1.y + g2.y + g3.y;
    }
    for (; p < p1; p++) {
        float2 g = h2s[csr[p]];
        a0 += g.x;
        a1 += g.y;
    }
    float di = dinv[i];
    out[i] = make_float2(fmaf(di, a0, b2[0]), fmaf(di, a1, b2[1]));
}

// ---------------- launch ----------------

extern "C" void kernel_launch(void* const* d_in, const int* in_sizes, int n_in,
                              void* d_out, int out_size, void* d_ws, size_t ws_size,
                              hipStream_t stream) {
    const float* x  = (const float*)d_in[0];
    const int*   ei = (const int*)d_in[1];
    const float* W1 = (const float*)d_in[2];
    const float* b1 = (const float*)d_in[3];
    const float* W2 = (const float*)d_in[4];
    const float* b2 = (const float*)d_in[5];
    float* out = (float*)d_out;

    const int* src = ei;
    const int* dst = ei + N_EDGES;

    char* ws = (char*)d_ws;
    size_t off = 0;
    auto alloc = [&](size_t bytes) -> void* {
        void* p = ws + off;
        off += (bytes + 255) & ~(size_t)255;
        return p;
    };
    _Float16* h1s   = (_Float16*)alloc((size_t)N_NODES * HIDDEN * 2);  // 25.6 MB
    int*      deg   = (int*)     alloc((size_t)N_NODES * 4);
    float*    dinv  = (float*)   alloc((size_t)N_NODES * 4);
    int*      rowptr= (int*)     alloc((size_t)(N_NODES + 1) * 4);
    int*      bcur  = (int*)     alloc((size_t)NBKT * 4);
    unsigned* csrt  = (unsigned*)alloc((size_t)N_EDGES * 4);           // 6.4 MB
    int*      csr   = (int*)     alloc((size_t)N_EDGES * 4);           // 6.4 MB
    _Float16* w1t   = (_Float16*)alloc((size_t)HIDDEN * KPAD * 2);     // 45 KB
    float2*   h2s   = (float2*)  alloc((size_t)N_NODES * 8);

    (void)hipMemsetAsync(deg, 0, (size_t)N_NODES * 4, stream);
    k_hist<<<(N_EDGES + 255) / 256, 256, 0, stream>>>(dst, deg);
    k_scan<<<1, 1024, 0, stream>>>(deg, rowptr, dinv);
    k_binit<<<2, 256, 0, stream>>>(rowptr, bcur);
    k_fill_bin<<<128, 256, 0, stream>>>(src, dst, bcur, csrt);
    k_sort<<<NBKT, 256, 0, stream>>>(rowptr, csrt, csr);
    k_w1t<<<(HIDDEN * KPAD + 255) / 256, 256, 0, stream>>>(W1, w1t);
    k_gemm1<<<(N_NODES / 16 + 3) / 4, 256, 0, stream>>>(x, w1t, dinv, h1s);
    k_agg1<<<N_NODES / 4, 256, 0, stream>>>((const __half2*)h1s, rowptr, csr, dinv, b1, W2, h2s);
    k_agg2<<<(N_NODES + 255) / 256, 256, 0, stream>>>(h2s, rowptr, csr, dinv, b2, (float2*)out);
}

// Round 6
// 371.419 us; speedup vs baseline: 1.6793x; 1.6793x over previous
//
#include <hip/hip_runtime.h>
#include <hip/hip_fp16.h>

#define N_NODES 100000
#define N_EDGES 1600000
#define IN_DIM  165
#define HIDDEN  128
#define OUT_DIM 2

#define NBKT 196        // ceil(100000/512) buckets of 512 nodes
#define CHUNK 8192      // edges per k_part block
#define KPAD 176        // 5*32 + 16

typedef _Float16 half8_t __attribute__((ext_vector_type(8)));
typedef _Float16 half4_t __attribute__((ext_vector_type(4)));
typedef float floatx4 __attribute__((ext_vector_type(4)));

// ---------------- degree histogram ----------------

__global__ void k_hist(const int* __restrict__ dst, int* __restrict__ deg) {
    int e = blockIdx.x * blockDim.x + threadIdx.x;
    if (e < N_EDGES) atomicAdd(&deg[dst[e]], 1);
}

// ---------------- scan: deg -> rowptr + dinv ----------------

__global__ __launch_bounds__(1024) void k_scan(const int* __restrict__ deg,
                                               int* __restrict__ rowptr,
                                               float* __restrict__ dinv) {
    __shared__ int wsum[16];
    __shared__ int chunk_total;
    const int NI4 = N_NODES / 4;              // 25000
    const int NCH = (NI4 + 1023) / 1024;      // 25
    int t = threadIdx.x;
    int lane = t & 63, wid = t >> 6;
    const int4* deg4 = (const int4*)deg;
    int running = 0;
    int idx4 = t;
    int4 cur = (idx4 < NI4) ? deg4[idx4] : make_int4(0, 0, 0, 0);
    for (int c = 0; c < NCH; c++) {
        int nidx4 = idx4 + 1024;
        int4 nxt = make_int4(0, 0, 0, 0);
        if (c + 1 < NCH && nidx4 < NI4) nxt = deg4[nidx4];
        int s = cur.x + cur.y + cur.z + cur.w;
        int inc = s;
        #pragma unroll
        for (int off = 1; off < 64; off <<= 1) {
            int y = __shfl_up(inc, off);
            if (lane >= off) inc += y;
        }
        if (lane == 63) wsum[wid] = inc;
        __syncthreads();
        if (t == 0) {
            int acc = 0;
            for (int w = 0; w < 16; w++) { int v = wsum[w]; wsum[w] = acc; acc += v; }
            chunk_total = acc;
        }
        __syncthreads();
        int e = running + wsum[wid] + (inc - s);
        if (idx4 < NI4) {
            int4 r;
            r.x = e;
            r.y = e + cur.x;
            r.z = r.y + cur.y;
            r.w = r.z + cur.z;
            ((int4*)rowptr)[idx4] = r;
            float4 dv;
            dv.x = rsqrtf((float)(cur.x + 1));
            dv.y = rsqrtf((float)(cur.y + 1));
            dv.z = rsqrtf((float)(cur.z + 1));
            dv.w = rsqrtf((float)(cur.w + 1));
            ((float4*)dinv)[idx4] = dv;
        }
        running += chunk_total;
        __syncthreads();
        cur = nxt;
        idx4 = nidx4;
    }
    if (t == 0) rowptr[N_NODES] = running;
}

// ---------------- bucket cursor init ----------------

__global__ void k_binit(const int* __restrict__ rowptr, int* __restrict__ bcursor) {
    int b = blockIdx.x * blockDim.x + threadIdx.x;
    if (b < NBKT) bcursor[b] = rowptr[b << 9];
}

// ---------------- phase 1: block-local counting sort by coarse bucket ----------------
// entry = src | (dst&511)<<17  (26 bits)

__global__ __launch_bounds__(256) void k_part(const int* __restrict__ src,
                                              const int* __restrict__ dst,
                                              int* __restrict__ bcursor,
                                              unsigned* __restrict__ csr_tmp) {
    __shared__ unsigned stage[CHUNK];   // 32 KB
    __shared__ int hist[256];           // counts (NBKT used)
    __shared__ int startv[256];         // exclusive scan
    __shared__ int lcur[256];           // scatter cursor
    __shared__ int gbase[256];          // claimed global base
    __shared__ int wsum[4];

    int t = threadIdx.x;
    int lane = t & 63, wid = t >> 6;
    int e0 = blockIdx.x * CHUNK;
    int nE = N_EDGES - e0; if (nE > CHUNK) nE = CHUNK;

    hist[t] = 0;
    __syncthreads();

    for (int i = t; i < nE; i += 256)
        atomicAdd(&hist[dst[e0 + i] >> 9], 1);
    __syncthreads();

    // 256-wide exclusive scan of hist
    int v = hist[t];
    int inc = v;
    #pragma unroll
    for (int off = 1; off < 64; off <<= 1) {
        int y = __shfl_up(inc, off);
        if (lane >= off) inc += y;
    }
    if (lane == 63) wsum[wid] = inc;
    __syncthreads();
    if (t == 0) {
        int acc = 0;
        #pragma unroll
        for (int w = 0; w < 4; w++) { int tv = wsum[w]; wsum[w] = acc; acc += tv; }
    }
    __syncthreads();
    int excl = wsum[wid] + inc - v;
    startv[t] = excl;
    lcur[t] = excl;
    if (t < NBKT && v > 0) gbase[t] = atomicAdd(&bcursor[t], v);
    __syncthreads();

    // scatter entries into LDS stage, grouped by bucket
    for (int i = t; i < nE; i += 256) {
        int d = dst[e0 + i];
        int s = src[e0 + i];
        int bk = d >> 9;
        unsigned entry = (unsigned)s | ((unsigned)(d & 511) << 17);
        int pos = atomicAdd(&lcur[bk], 1);
        stage[pos] = entry;
    }
    __syncthreads();

    // coalesced per-segment write-out (wave per bucket round-robin)
    for (int bk = wid; bk < NBKT; bk += 4) {
        int cnt = hist[bk];
        int lo = startv[bk];
        int gb = gbase[bk];
        for (int j = lane; j < cnt; j += 64)
            csr_tmp[gb + j] = stage[lo + j];
    }
}

// ---------------- phase 2: in-bucket counting sort -> final CSR (src only) ----------------

__global__ __launch_bounds__(256) void k_sort2(const int* __restrict__ rowptr,
                                               const unsigned* __restrict__ csr_tmp,
                                               int* __restrict__ csr) {
    __shared__ int cur[512];
    int b = blockIdx.x;
    int n0 = b << 9;
    int t = threadIdx.x;
    #pragma unroll
    for (int j = 0; j < 2; j++) {
        int node = n0 + t + j * 256;
        cur[t + j * 256] = (node < N_NODES) ? rowptr[node] : 0;
    }
    int rbase = rowptr[n0];
    int rend  = rowptr[min(n0 + 512, N_NODES)];
    __syncthreads();
    for (int p = rbase + t; p < rend; p += 256) {
        unsigned entry = csr_tmp[p];
        int local = (int)(entry >> 17);
        int s = (int)(entry & 0x1FFFFu);
        int pos = atomicAdd(&cur[local], 1);
        csr[pos] = s;   // scatter confined to this bucket's ~33KB region
    }
}

// ---------------- W1 transpose to fp16 [col][KPAD] ----------------

__global__ void k_w1t(const float* __restrict__ W1, _Float16* __restrict__ w1t) {
    int idx = blockIdx.x * 256 + threadIdx.x;
    if (idx < HIDDEN * KPAD) {
        int c = idx / KPAD, k = idx - c * KPAD;
        float v = (k < IN_DIM) ? W1[k * HIDDEN + c] : 0.f;
        w1t[idx] = (_Float16)v;
    }
}

// ---------------- GEMM1 (f16 MFMA): h1s = dinv * (x @ W1), fp16 out ----------------
// One wave per 16-row strip; A from global x (fp32->fp16), B from L2-resident W1T.

__global__ __launch_bounds__(256) void k_gemm1(const float* __restrict__ x,
                                               const _Float16* __restrict__ w1t,
                                               const float* __restrict__ dinv,
                                               _Float16* __restrict__ h1s) {
    int t = threadIdx.x;
    int wid = t >> 6, lane = t & 63;
    int row0 = (blockIdx.x * 4 + wid) * 16;
    if (row0 >= N_NODES) return;
    int m = lane & 15;
    int quad = lane >> 4;
    const float* xrow = x + (size_t)(row0 + m) * IN_DIM;

    floatx4 acc[8];
    #pragma unroll
    for (int i = 0; i < 8; i++) acc[i] = (floatx4)(0.f);

    #pragma unroll 1
    for (int kc = 0; kc < 5; kc++) {
        int kb = kc * 32 + quad * 8;
        half8_t a;
        #pragma unroll
        for (int j = 0; j < 8; j++) a[j] = (_Float16)xrow[kb + j];
        #pragma unroll
        for (int cb = 0; cb < 8; cb++) {
            int col = cb * 16 + m;
            half8_t bf = *(const half8_t*)&w1t[col * KPAD + kb];
            acc[cb] = __builtin_amdgcn_mfma_f32_16x16x32_f16(a, bf, acc[cb], 0, 0, 0);
        }
    }
    // K tail: 160..164 via 16x16x16 (k = quad*4 + j)
    {
        int kb = 160 + quad * 4;
        half4_t a;
        #pragma unroll
        for (int j = 0; j < 4; j++)
            a[j] = (kb + j < IN_DIM) ? (_Float16)xrow[kb + j] : (_Float16)0.f;
        #pragma unroll
        for (int cb = 0; cb < 8; cb++) {
            int col = cb * 16 + m;
            half4_t bf = *(const half4_t*)&w1t[col * KPAD + kb];
            acc[cb] = __builtin_amdgcn_mfma_f32_16x16x16f16(a, bf, acc[cb], 0, 0, 0);
        }
    }
    // epilogue: scale by dinv[row], store fp16 (C/D: col=lane&15, row=quad*4+reg)
    float dv[4];
    #pragma unroll
    for (int r = 0; r < 4; r++) dv[r] = dinv[row0 + quad * 4 + r];
    #pragma unroll
    for (int cb = 0; cb < 8; cb++) {
        #pragma unroll
        for (int r = 0; r < 4; r++) {
            h1s[(size_t)(row0 + quad * 4 + r) * HIDDEN + cb * 16 + m] =
                (_Float16)(acc[cb][r] * dv[r]);
        }
    }
}

// ---------------- Fused agg1 + bias + ReLU + W2 (128->2), weightless sum ----------------
// One wave per node; lane f owns features 2f,2f+1. h2s = dinv * (relu(z) @ W2).

__global__ __launch_bounds__(256) void k_agg1(const __half2* __restrict__ h1,
                                              const int* __restrict__ rowptr,
                                              const int* __restrict__ csr,
                                              const float* __restrict__ dinv,
                                              const float* __restrict__ b1,
                                              const float* __restrict__ W2,
                                              float2* __restrict__ h2s) {
    int node = blockIdx.x * 4 + (threadIdx.x >> 6);
    int f = threadIdx.x & 63;
    float2 self = __half22float2(h1[node * 64 + f]);
    float accx = self.x, accy = self.y;
    int p0 = rowptr[node], p1 = rowptr[node + 1];

    int p = p0;
    for (; p + 7 < p1; p += 8) {
        int s[8];
        #pragma unroll
        for (int j = 0; j < 8; j++) s[j] = csr[p + j];
        __half2 g[8];
        #pragma unroll
        for (int j = 0; j < 8; j++) g[j] = h1[s[j] * 64 + f];
        #pragma unroll
        for (int j = 0; j < 8; j++) {
            float2 gf = __half22float2(g[j]);
            accx += gf.x;
            accy += gf.y;
        }
    }
    for (; p < p1; p++) {
        float2 gf = __half22float2(h1[csr[p] * 64 + f]);
        accx += gf.x;
        accy += gf.y;
    }

    float di = dinv[node];
    float2 bb = ((const float2*)b1)[f];
    float z0 = fmaf(di, accx, bb.x);
    float z1 = fmaf(di, accy, bb.y);
    float r0 = fmaxf(z0, 0.f);
    float r1 = fmaxf(z1, 0.f);
    float4 w2v = ((const float4*)W2)[f];
    float a0 = r0 * w2v.x + r1 * w2v.z;
    float a1 = r0 * w2v.y + r1 * w2v.w;
    #pragma unroll
    for (int off = 32; off; off >>= 1) {
        a0 += __shfl_down(a0, off);
        a1 += __shfl_down(a1, off);
    }
    if (f == 0) h2s[node] = make_float2(di * a0, di * a1);
}

// ---------------- agg2: out = b2 + dinv_i*(h2s_i + sum h2s_src) ----------------

__global__ void k_agg2(const float2* __restrict__ h2s, const int* __restrict__ rowptr,
                       const int* __restrict__ csr, const float* __restrict__ dinv,
                       const float* __restrict__ b2, float2* __restrict__ out) {
    int i = blockIdx.x * blockDim.x + threadIdx.x;
    if (i >= N_NODES) return;
    float2 self = h2s[i];
    float a0 = self.x, a1 = self.y;
    int p0 = rowptr[i], p1 = rowptr[i + 1];
    int p = p0;
    for (; p + 3 < p1; p += 4) {
        int s0 = csr[p], s1 = csr[p + 1], s2 = csr[p + 2], s3 = csr[p + 3];
        float2 g0 = h2s[s0], g1 = h2s[s1], g2 = h2s[s2], g3 = h2s[s3];
        a0 += g0.x + g1.x + g2.x + g3.x;
        a1 += g0.y + g1.y + g2.y + g3.y;
    }
    for (; p < p1; p++) {
        float2 g = h2s[csr[p]];
        a0 += g.x;
        a1 += g.y;
    }
    float di = dinv[i];
    out[i] = make_float2(fmaf(di, a0, b2[0]), fmaf(di, a1, b2[1]));
}

// ---------------- launch ----------------

extern "C" void kernel_launch(void* const* d_in, const int* in_sizes, int n_in,
                              void* d_out, int out_size, void* d_ws, size_t ws_size,
                              hipStream_t stream) {
    const float* x  = (const float*)d_in[0];
    const int*   ei = (const int*)d_in[1];
    const float* W1 = (const float*)d_in[2];
    const float* b1 = (const float*)d_in[3];
    const float* W2 = (const float*)d_in[4];
    const float* b2 = (const float*)d_in[5];
    float* out = (float*)d_out;

    const int* src = ei;
    const int* dst = ei + N_EDGES;

    char* ws = (char*)d_ws;
    size_t off = 0;
    auto alloc = [&](size_t bytes) -> void* {
        void* p = ws + off;
        off += (bytes + 255) & ~(size_t)255;
        return p;
    };
    _Float16* h1s   = (_Float16*)alloc((size_t)N_NODES * HIDDEN * 2);  // 25.6 MB
    int*      deg   = (int*)     alloc((size_t)N_NODES * 4);
    float*    dinv  = (float*)   alloc((size_t)N_NODES * 4);
    int*      rowptr= (int*)     alloc((size_t)(N_NODES + 1) * 4);
    int*      bcur  = (int*)     alloc((size_t)NBKT * 4);
    unsigned* csrt  = (unsigned*)alloc((size_t)N_EDGES * 4);           // 6.4 MB
    int*      csr   = (int*)     alloc((size_t)N_EDGES * 4);           // 6.4 MB
    _Float16* w1t   = (_Float16*)alloc((size_t)HIDDEN * KPAD * 2);     // 45 KB
    float2*   h2s   = (float2*)  alloc((size_t)N_NODES * 8);

    const int nchunks = (N_EDGES + CHUNK - 1) / CHUNK;  // 196

    (void)hipMemsetAsync(deg, 0, (size_t)N_NODES * 4, stream);
    k_hist<<<(N_EDGES + 255) / 256, 256, 0, stream>>>(dst, deg);
    k_scan<<<1, 1024, 0, stream>>>(deg, rowptr, dinv);
    k_binit<<<1, 256, 0, stream>>>(rowptr, bcur);
    k_part<<<nchunks, 256, 0, stream>>>(src, dst, bcur, csrt);
    k_sort2<<<NBKT, 256, 0, stream>>>(rowptr, csrt, csr);
    k_w1t<<<(HIDDEN * KPAD + 255) / 256, 256, 0, stream>>>(W1, w1t);
    k_gemm1<<<(N_NODES / 16 + 3) / 4, 256, 0, stream>>>(x, w1t, dinv, h1s);
    k_agg1<<<N_NODES / 4, 256, 0, stream>>>((const __half2*)h1s, rowptr, csr, dinv, b1, W2, h2s);
    k_agg2<<<(N_NODES + 255) / 256, 256, 0, stream>>>(h2s, rowptr, csr, dinv, b2, (float2*)out);
}